// Round 4
// baseline (225.106 us; speedup 1.0000x reference)
//
#include <hip/hip_runtime.h>
#include <math.h>

#define B_ROWS 8192
#define DIM 64
#define NCODES 2048
#define NSPLIT 16                             // code-range splits (split-K)
#define CODES_PER_SPLIT (NCODES / NSPLIT)     // 128
#define TILES_PER_WAVE (CODES_PER_SPLIT / 16) // 8 tiles of 16 codes
#define NRB (B_ROWS / 128)                    // 64 row-blocks
#define EPSF 1e-6f
#define BETA 0.25f
#define V_VAL 0.125f                          // 1/sqrt(64)

typedef __attribute__((ext_vector_type(8))) short sh8;    // 8 bf16 = 4 VGPR
typedef __attribute__((ext_vector_type(4))) float f32x4;  // MFMA acc

__device__ __forceinline__ float wave_sum64(float v) {
#pragma unroll
    for (int m = 32; m >= 1; m >>= 1) v += __shfl_xor(v, m, 64);
    return v;
}

// RNE float -> bf16 bit trick (inputs finite)
__device__ __forceinline__ unsigned short f2bf(float f) {
    unsigned u = __float_as_uint(f);
    unsigned r = (u + 0x7fffu + ((u >> 16) & 1u)) >> 16;
    return (unsigned short)r;
}
__device__ __forceinline__ float bf2f(unsigned short h) {
    return __uint_as_float(((unsigned)h) << 16);
}

// Fragment layout (verified R3): frag #((tile16*3 + split)*2 + khalf) is
// 64 lanes x 16B; element (lane, j) = split_s(src[tile16*16 + (lane&15)]
// [khalf*32 + (lane>>4)*8 + j]). Writer: tile=rc>>4, m=rc&15, h=dim>>5,
// q=(dim>>3)&3, j=dim&7, lane'=q*16+m.
__device__ __forceinline__ void write_frag3(unsigned short* frag, int rc,
                                            int dim, float val) {
    unsigned short s0 = f2bf(val);
    float r = val - bf2f(s0);
    unsigned short s1 = f2bf(r);
    r -= bf2f(s1);
    unsigned short s2 = f2bf(r);
    int t = rc >> 4, m = rc & 15;
    int h = dim >> 5, q = (dim >> 3) & 3, j = dim & 7;
    int lanep = q * 16 + m;
    size_t base = ((size_t)(t * 3) * 2 + h) * 512 + (size_t)lanep * 8 + j;
    frag[base] = s0;
    frag[base + 2 * 512] = s1;
    frag[base + 4 * 512] = s2;
}

// Kernel 1: fused prep. Blocks [0,512): code norms + code fragments (+ zero
// counters/loss). Blocks [512,2560): row rotation factors + x_canonical
// fragments (rank-2 R^T x, R never materialized).
__global__ __launch_bounds__(256) void rq_prep(
        const float* __restrict__ x,
        const float* __restrict__ pq,
        const float* __restrict__ codes,
        float* __restrict__ cn,
        unsigned short* __restrict__ cfrag,
        unsigned short* __restrict__ xfrag,
        float* __restrict__ uo,
        float* __restrict__ duv,
        int* __restrict__ cnt,
        float* __restrict__ out_loss) {
    int tid = threadIdx.x;
    int lane = tid & 63;
    int w = tid >> 6;

    if (blockIdx.x < NCODES / 4) {
        int c = blockIdx.x * 4 + w;
        float cv = codes[(size_t)c * DIM + lane];
        float s = wave_sum64(cv * cv);
        if (lane == 0) cn[c] = s;
        write_frag3(cfrag, c, lane, cv);
        if (blockIdx.x == 0) {
            if (tid < NRB) cnt[tid] = 0;
            if (tid == NRB) *out_loss = 0.0f;
        }
    } else {
        int r = (blockIdx.x - NCODES / 4) * 4 + w;
        float xv = x[(size_t)r * DIM + lane];
        float qv = pq[(size_t)r * DIM + lane];
        float n2 = wave_sum64(qv * qv);
        float inv = 1.0f / fmaxf(sqrtf(n2), EPSF);
        float uv = qv * inv;
        float d = V_VAL * wave_sum64(uv);
        float a = wave_sum64(uv * xv);
        float b = V_VAL * wave_sum64(xv);
        float den = 1.0f + d + EPSF;
        float cu = -b + (d * b - a) / den;
        float cv = a - (b - d * a) / den;
        float xcv = xv + uv * cu + V_VAL * cv;
        uo[(size_t)r * DIM + lane] = uv;
        if (lane == 0) duv[r] = d;
        write_frag3(xfrag, r, lane, xcv);
    }
}

// Kernel 2: MFMA distance scan + split-K fixup epilogue.
// Block = (row-block rb of 128 rows) x (code-split cs of 128 codes).
// Wave = 32 rows (2 A-tile sets, bf16x3 resident) x 8 tiles of 16 codes;
// 6 split-products x 2 K-halves chained into fp32 acc -> exact-fp32-class
// dot. Partials to pd/pi[row*16+cs] (coalesced for the reader). Last block
// per rb (device-scope counter) combines, gathers the code, rotates back
// (rank-2 R q), writes quantized/index and one loss atomicAdd per rb.
__global__ __launch_bounds__(256) void rq_dist_fused(
        const unsigned short* __restrict__ xfrag,
        const unsigned short* __restrict__ cfrag,
        const float* __restrict__ cn,
        const float* __restrict__ codes,
        const float* __restrict__ uo,
        const float* __restrict__ duv,
        const float* __restrict__ x,
        float* __restrict__ pd,
        int* __restrict__ pi,
        int* __restrict__ cnt,
        float* __restrict__ out_q,
        float* __restrict__ out_idx,
        float* __restrict__ out_loss) {
    __shared__ int s_flag;
    __shared__ float s_part[4];

    int tid = threadIdx.x;
    int lane = tid & 63;
    int w = tid >> 6;
    int rb = blockIdx.x >> 4;
    int cs = blockIdx.x & (NSPLIT - 1);
    int r0 = rb * 128 + w * 32;
    int rt0 = r0 >> 4;

    const sh8* xf = (const sh8*)xfrag;
    const sh8* cf = (const sh8*)cfrag;

    sh8 afr[2][3][2];
#pragma unroll
    for (int rs = 0; rs < 2; ++rs)
#pragma unroll
        for (int s = 0; s < 3; ++s)
#pragma unroll
            for (int h = 0; h < 2; ++h)
                afr[rs][s][h] = xf[(size_t)(((rt0 + rs) * 3 + s) * 2 + h) * 64 + lane];

    float bv0[4], bv1[4];
    int bi0[4], bi1[4];
#pragma unroll
    for (int i = 0; i < 4; ++i) {
        bv0[i] = INFINITY; bv1[i] = INFINITY;
        bi0[i] = 0x7fffffff; bi1[i] = 0x7fffffff;
    }

    int cbase = cs * CODES_PER_SPLIT;
    for (int t = 0; t < TILES_PER_WAVE; ++t) {
        int c0 = cbase + t * 16;
        int ct = c0 >> 4;
        sh8 bfr[3][2];
#pragma unroll
        for (int s = 0; s < 3; ++s)
#pragma unroll
            for (int h = 0; h < 2; ++h)
                bfr[s][h] = cf[(size_t)((ct * 3 + s) * 2 + h) * 64 + lane];

        f32x4 acc0 = {0.f, 0.f, 0.f, 0.f};
        f32x4 acc1 = {0.f, 0.f, 0.f, 0.f};
#pragma unroll
        for (int h = 0; h < 2; ++h) {
            acc0 = __builtin_amdgcn_mfma_f32_16x16x32_bf16(afr[0][2][h], bfr[0][h], acc0, 0, 0, 0);
            acc0 = __builtin_amdgcn_mfma_f32_16x16x32_bf16(afr[0][1][h], bfr[1][h], acc0, 0, 0, 0);
            acc0 = __builtin_amdgcn_mfma_f32_16x16x32_bf16(afr[0][0][h], bfr[2][h], acc0, 0, 0, 0);
            acc0 = __builtin_amdgcn_mfma_f32_16x16x32_bf16(afr[0][1][h], bfr[0][h], acc0, 0, 0, 0);
            acc0 = __builtin_amdgcn_mfma_f32_16x16x32_bf16(afr[0][0][h], bfr[1][h], acc0, 0, 0, 0);
            acc0 = __builtin_amdgcn_mfma_f32_16x16x32_bf16(afr[0][0][h], bfr[0][h], acc0, 0, 0, 0);

            acc1 = __builtin_amdgcn_mfma_f32_16x16x32_bf16(afr[1][2][h], bfr[0][h], acc1, 0, 0, 0);
            acc1 = __builtin_amdgcn_mfma_f32_16x16x32_bf16(afr[1][1][h], bfr[1][h], acc1, 0, 0, 0);
            acc1 = __builtin_amdgcn_mfma_f32_16x16x32_bf16(afr[1][0][h], bfr[2][h], acc1, 0, 0, 0);
            acc1 = __builtin_amdgcn_mfma_f32_16x16x32_bf16(afr[1][1][h], bfr[0][h], acc1, 0, 0, 0);
            acc1 = __builtin_amdgcn_mfma_f32_16x16x32_bf16(afr[1][0][h], bfr[1][h], acc1, 0, 0, 0);
            acc1 = __builtin_amdgcn_mfma_f32_16x16x32_bf16(afr[1][0][h], bfr[0][h], acc1, 0, 0, 0);
        }

        float cnv = cn[c0 + (lane & 15)];
        int idxv = c0 + (lane & 15);
#pragma unroll
        for (int reg = 0; reg < 4; ++reg) {
            float s0 = fmaf(-2.0f, acc0[reg], cnv);
            if (s0 < bv0[reg]) { bv0[reg] = s0; bi0[reg] = idxv; }
            float s1 = fmaf(-2.0f, acc1[reg], cnv);
            if (s1 < bv1[reg]) { bv1[reg] = s1; bi1[reg] = idxv; }
        }
    }

    // Per-row 16-col reduction (lexicographic -> first-occurrence), store
    // partial at pd[row*NSPLIT+cs] (one cache line per row for the reader).
#pragma unroll
    for (int rs = 0; rs < 2; ++rs) {
#pragma unroll
        for (int reg = 0; reg < 4; ++reg) {
            float v = rs ? bv1[reg] : bv0[reg];
            int ix = rs ? bi1[reg] : bi0[reg];
#pragma unroll
            for (int m = 1; m < 16; m <<= 1) {
                float ov = __shfl_xor(v, m, 64);
                int oi = __shfl_xor(ix, m, 64);
                if (ov < v || (ov == v && oi < ix)) { v = ov; ix = oi; }
            }
            int row = r0 + rs * 16 + (lane >> 4) * 4 + reg;
            if ((lane & 15) == reg) {
                pd[(size_t)row * NSPLIT + cs] = v;
                pi[(size_t)row * NSPLIT + cs] = ix;
            }
        }
    }

    // --- split-K fixup: last block for this rb does the epilogue ---
    __syncthreads();                 // all waves' partial stores drained
    if (tid == 0) {
        __threadfence();             // release: publish pd/pi device-wide
        int old = atomicAdd(&cnt[rb], 1);
        s_flag = (old == NSPLIT - 1) ? 1 : 0;
    }
    __syncthreads();
    if (!s_flag) return;
    __threadfence();                 // acquire: invalidate stale cache

    float lsum = 0.f;
    for (int i = 0; i < 32; ++i) {
        int row = rb * 128 + w * 32 + i;
        float pv = INFINITY;
        int iv = 0x7fffffff;
        if (lane < NSPLIT) {
            pv = pd[(size_t)row * NSPLIT + lane];
            iv = pi[(size_t)row * NSPLIT + lane];
        }
#pragma unroll
        for (int m = 1; m < NSPLIT; m <<= 1) {
            float ov = __shfl_xor(pv, m, 64);
            int oi = __shfl_xor(iv, m, 64);
            if (ov < pv || (ov == pv && oi < iv)) { pv = ov; iv = oi; }
        }
        int idx = __shfl(iv, 0, 64);

        float qc = codes[(size_t)idx * DIM + lane];
        float uvv = uo[(size_t)row * DIM + lane];
        float xv = x[(size_t)row * DIM + lane];
        float dv = duv[row];

        float aq = wave_sum64(uvv * qc);
        float bq = V_VAL * wave_sum64(qc);
        float den = 1.0f + dv + EPSF;
        float cu = bq + (dv * bq - aq) / den;
        float cw = -aq - (bq - dv * aq) / den;
        out_q[(size_t)row * DIM + lane] = qc + uvv * cu + V_VAL * cw;

        float diff = xv - qc;
        lsum += diff * diff;
        if (lane == 0) out_idx[row] = (float)idx;
    }
    lsum = wave_sum64(lsum);
    if (lane == 0) s_part[w] = lsum;
    __syncthreads();
    if (tid == 0) {
        float t = (s_part[0] + s_part[1]) + (s_part[2] + s_part[3]);
        atomicAdd(out_loss, t * (1.0f + BETA) * (1.0f / (float)B_ROWS));
    }
}

extern "C" void kernel_launch(void* const* d_in, const int* in_sizes, int n_in,
                              void* d_out, int out_size, void* d_ws, size_t ws_size,
                              hipStream_t stream) {
    const float* x     = (const float*)d_in[0];
    const float* pq    = (const float*)d_in[1];
    const float* codes = (const float*)d_in[2];

    float* out      = (float*)d_out;
    float* out_q    = out;                         // B*D
    float* out_idx  = out + (size_t)B_ROWS * DIM;  // B
    float* out_loss = out_idx + B_ROWS;            // 1

    char* ws = (char*)d_ws;
    const size_t MB = 1024 * 1024;
    float* uo            = (float*)ws;                          // 2 MB
    float* duv           = (float*)(ws + 2 * MB);               // 32 KB
    float* cn            = (float*)(ws + 2 * MB + 64 * 1024);   // 8 KB
    int*   cnt           = (int*)(ws + 2 * MB + 128 * 1024);    // 256 B
    unsigned short* xfrg = (unsigned short*)(ws + 3 * MB);      // 3 MB
    unsigned short* cfrg = (unsigned short*)(ws + 6 * MB);      // 768 KB
    float* pd            = (float*)(ws + 7 * MB);               // 512 KB
    int*   pi            = (int*)(ws + 7 * MB + 512 * 1024);    // 512 KB

    rq_prep<<<NCODES / 4 + B_ROWS / 4, 256, 0, stream>>>(
        x, pq, codes, cn, cfrg, xfrg, uo, duv, cnt, out_loss);
    rq_dist_fused<<<NRB * NSPLIT, 256, 0, stream>>>(
        xfrg, cfrg, cn, codes, uo, duv, x, pd, pi, cnt,
        out_q, out_idx, out_loss);
}

// Round 5
// 97.037 us; speedup vs baseline: 2.3198x; 2.3198x over previous
//
#include <hip/hip_runtime.h>
#include <math.h>

#define B_ROWS 8192
#define DIM 64
#define NCODES 2048
#define NSPLIT 16                             // code-range splits (split-K)
#define CODES_PER_SPLIT (NCODES / NSPLIT)     // 128
#define TILES_PER_WAVE (CODES_PER_SPLIT / 16) // 8 tiles of 16 codes
#define EPSF 1e-6f
#define BETA 0.25f
#define V_VAL 0.125f                          // 1/sqrt(64)

typedef __attribute__((ext_vector_type(8))) short sh8;    // 8 bf16 = 4 VGPR
typedef __attribute__((ext_vector_type(4))) float f32x4;  // MFMA acc

__device__ __forceinline__ float wave_sum64(float v) {
#pragma unroll
    for (int m = 32; m >= 1; m >>= 1) v += __shfl_xor(v, m, 64);
    return v;
}

// RNE float -> bf16 bit trick (inputs finite)
__device__ __forceinline__ unsigned short f2bf(float f) {
    unsigned u = __float_as_uint(f);
    unsigned r = (u + 0x7fffu + ((u >> 16) & 1u)) >> 16;
    return (unsigned short)r;
}
__device__ __forceinline__ float bf2f(unsigned short h) {
    return __uint_as_float(((unsigned)h) << 16);
}

// Fragment layout (verified R3): frag #((tile16*3 + split)*2 + khalf) is
// 64 lanes x 16B; element (lane, j) = split_s(src[tile16*16 + (lane&15)]
// [khalf*32 + (lane>>4)*8 + j]).
__device__ __forceinline__ void write_frag3(unsigned short* frag, int rc,
                                            int dim, float val) {
    unsigned short s0 = f2bf(val);
    float r = val - bf2f(s0);
    unsigned short s1 = f2bf(r);
    r -= bf2f(s1);
    unsigned short s2 = f2bf(r);
    int t = rc >> 4, m = rc & 15;
    int h = dim >> 5, q = (dim >> 3) & 3, j = dim & 7;
    int lanep = q * 16 + m;
    size_t base = ((size_t)(t * 3) * 2 + h) * 512 + (size_t)lanep * 8 + j;
    frag[base] = s0;
    frag[base + 2 * 512] = s1;
    frag[base + 4 * 512] = s2;
}

// Kernel 1: fused prep. Blocks [0,512): code norms + bf16x3 code fragments
// (+ zero loss). Blocks [512,2560): row rotation factors + x_canonical
// fragments (rank-2 R^T x, R never materialized).
__global__ __launch_bounds__(256) void rq_prep(
        const float* __restrict__ x,
        const float* __restrict__ pq,
        const float* __restrict__ codes,
        float* __restrict__ cn,
        unsigned short* __restrict__ cfrag,
        unsigned short* __restrict__ xfrag,
        float* __restrict__ uo,
        float* __restrict__ duv,
        float* __restrict__ out_loss) {
    int tid = threadIdx.x;
    int lane = tid & 63;
    int w = tid >> 6;

    if (blockIdx.x < NCODES / 4) {
        int c = blockIdx.x * 4 + w;
        float cv = codes[(size_t)c * DIM + lane];
        float s = wave_sum64(cv * cv);
        if (lane == 0) cn[c] = s;
        write_frag3(cfrag, c, lane, cv);
        if (blockIdx.x == 0 && tid == 0) *out_loss = 0.0f;
    } else {
        int r = (blockIdx.x - NCODES / 4) * 4 + w;
        float xv = x[(size_t)r * DIM + lane];
        float qv = pq[(size_t)r * DIM + lane];
        float n2 = wave_sum64(qv * qv);
        float inv = 1.0f / fmaxf(sqrtf(n2), EPSF);
        float uv = qv * inv;
        float d = V_VAL * wave_sum64(uv);
        float a = wave_sum64(uv * xv);
        float b = V_VAL * wave_sum64(xv);
        float den = 1.0f + d + EPSF;
        float cu = -b + (d * b - a) / den;
        float cv = a - (b - d * a) / den;
        float xcv = xv + uv * cu + V_VAL * cv;
        uo[(size_t)r * DIM + lane] = uv;
        if (lane == 0) duv[r] = d;
        write_frag3(xfrag, r, lane, xcv);
    }
}

// Kernel 2: MFMA distance scan (R3's proven structure, NO fences).
// Wave = 32 rows (2 A-tile sets, bf16x3 resident in 48 VGPRs) x 128 codes
// (8 tiles of 16). 6 split-products x 2 K-halves chained into fp32 acc ->
// exact-fp32-class dot. Partials stored at pd[row*16+cs] (one cache line
// per row for the epilogue reader).
__global__ __launch_bounds__(256) void rq_dist_mfma(
        const unsigned short* __restrict__ xfrag,
        const unsigned short* __restrict__ cfrag,
        const float* __restrict__ cn,
        float* __restrict__ pd,
        int* __restrict__ pi) {
    int tid = threadIdx.x;
    int lane = tid & 63;
    int w = tid >> 6;
    int rb = blockIdx.x >> 4;     // 64 row-blocks of 128 rows
    int cs = blockIdx.x & (NSPLIT - 1);
    int r0 = rb * 128 + w * 32;
    int rt0 = r0 >> 4;

    const sh8* xf = (const sh8*)xfrag;
    const sh8* cf = (const sh8*)cfrag;

    sh8 afr[2][3][2];
#pragma unroll
    for (int rs = 0; rs < 2; ++rs)
#pragma unroll
        for (int s = 0; s < 3; ++s)
#pragma unroll
            for (int h = 0; h < 2; ++h)
                afr[rs][s][h] = xf[(size_t)(((rt0 + rs) * 3 + s) * 2 + h) * 64 + lane];

    float bv0[4], bv1[4];
    int bi0[4], bi1[4];
#pragma unroll
    for (int i = 0; i < 4; ++i) {
        bv0[i] = INFINITY; bv1[i] = INFINITY;
        bi0[i] = 0x7fffffff; bi1[i] = 0x7fffffff;
    }

    int cbase = cs * CODES_PER_SPLIT;
    for (int t = 0; t < TILES_PER_WAVE; ++t) {
        int c0 = cbase + t * 16;
        int ct = c0 >> 4;
        sh8 bfr[3][2];
#pragma unroll
        for (int s = 0; s < 3; ++s)
#pragma unroll
            for (int h = 0; h < 2; ++h)
                bfr[s][h] = cf[(size_t)((ct * 3 + s) * 2 + h) * 64 + lane];

        f32x4 acc0 = {0.f, 0.f, 0.f, 0.f};
        f32x4 acc1 = {0.f, 0.f, 0.f, 0.f};
#pragma unroll
        for (int h = 0; h < 2; ++h) {
            acc0 = __builtin_amdgcn_mfma_f32_16x16x32_bf16(afr[0][2][h], bfr[0][h], acc0, 0, 0, 0);
            acc0 = __builtin_amdgcn_mfma_f32_16x16x32_bf16(afr[0][1][h], bfr[1][h], acc0, 0, 0, 0);
            acc0 = __builtin_amdgcn_mfma_f32_16x16x32_bf16(afr[0][0][h], bfr[2][h], acc0, 0, 0, 0);
            acc0 = __builtin_amdgcn_mfma_f32_16x16x32_bf16(afr[0][1][h], bfr[0][h], acc0, 0, 0, 0);
            acc0 = __builtin_amdgcn_mfma_f32_16x16x32_bf16(afr[0][0][h], bfr[1][h], acc0, 0, 0, 0);
            acc0 = __builtin_amdgcn_mfma_f32_16x16x32_bf16(afr[0][0][h], bfr[0][h], acc0, 0, 0, 0);

            acc1 = __builtin_amdgcn_mfma_f32_16x16x32_bf16(afr[1][2][h], bfr[0][h], acc1, 0, 0, 0);
            acc1 = __builtin_amdgcn_mfma_f32_16x16x32_bf16(afr[1][1][h], bfr[1][h], acc1, 0, 0, 0);
            acc1 = __builtin_amdgcn_mfma_f32_16x16x32_bf16(afr[1][0][h], bfr[2][h], acc1, 0, 0, 0);
            acc1 = __builtin_amdgcn_mfma_f32_16x16x32_bf16(afr[1][1][h], bfr[0][h], acc1, 0, 0, 0);
            acc1 = __builtin_amdgcn_mfma_f32_16x16x32_bf16(afr[1][0][h], bfr[1][h], acc1, 0, 0, 0);
            acc1 = __builtin_amdgcn_mfma_f32_16x16x32_bf16(afr[1][0][h], bfr[0][h], acc1, 0, 0, 0);
        }

        float cnv = cn[c0 + (lane & 15)];
        int idxv = c0 + (lane & 15);
#pragma unroll
        for (int reg = 0; reg < 4; ++reg) {
            float s0 = fmaf(-2.0f, acc0[reg], cnv);
            if (s0 < bv0[reg]) { bv0[reg] = s0; bi0[reg] = idxv; }
            float s1 = fmaf(-2.0f, acc1[reg], cnv);
            if (s1 < bv1[reg]) { bv1[reg] = s1; bi1[reg] = idxv; }
        }
    }

    // Per-row 16-col reduction (lexicographic -> first-occurrence).
#pragma unroll
    for (int rs = 0; rs < 2; ++rs) {
#pragma unroll
        for (int reg = 0; reg < 4; ++reg) {
            float v = rs ? bv1[reg] : bv0[reg];
            int ix = rs ? bi1[reg] : bi0[reg];
#pragma unroll
            for (int m = 1; m < 16; m <<= 1) {
                float ov = __shfl_xor(v, m, 64);
                int oi = __shfl_xor(ix, m, 64);
                if (ov < v || (ov == v && oi < ix)) { v = ov; ix = oi; }
            }
            int row = r0 + rs * 16 + (lane >> 4) * 4 + reg;
            if ((lane & 15) == reg) {
                pd[(size_t)row * NSPLIT + cs] = v;
                pi[(size_t)row * NSPLIT + cs] = ix;
            }
        }
    }
}

// Kernel 3: fused epilogue + loss. 128 blocks x 512 threads (8 waves ->
// 2 waves/SIMD). Wave handles 8 rows: combine 16 partials/row (one cache
// line), gather code, rotate back (rank-2 R q), write quantized + index,
// accumulate loss; block-reduce -> ONE atomicAdd per block (128 total).
__global__ __launch_bounds__(512) void rq_epilogue(
        const float* __restrict__ x,
        const float* __restrict__ codes,
        const float* __restrict__ uo,
        const float* __restrict__ duv,
        const float* __restrict__ pd,
        const int* __restrict__ pi,
        float* __restrict__ out_q,
        float* __restrict__ out_idx,
        float* __restrict__ out_loss) {
    __shared__ float s_part[8];
    int tid = threadIdx.x;
    int lane = tid & 63;
    int w = tid >> 6;
    int row0 = blockIdx.x * 64 + w * 8;

    float lsum = 0.f;
#pragma unroll
    for (int i = 0; i < 8; ++i) {
        int row = row0 + i;
        float pv = INFINITY;
        int iv = 0x7fffffff;
        if (lane < NSPLIT) {
            pv = pd[(size_t)row * NSPLIT + lane];
            iv = pi[(size_t)row * NSPLIT + lane];
        }
#pragma unroll
        for (int m = 1; m < NSPLIT; m <<= 1) {
            float ov = __shfl_xor(pv, m, 64);
            int oi = __shfl_xor(iv, m, 64);
            if (ov < pv || (ov == pv && oi < iv)) { pv = ov; iv = oi; }
        }
        int idx = __shfl(iv, 0, 64);

        float qc = codes[(size_t)idx * DIM + lane];
        float uvv = uo[(size_t)row * DIM + lane];
        float xv = x[(size_t)row * DIM + lane];
        float dv = duv[row];

        float aq = wave_sum64(uvv * qc);
        float bq = V_VAL * wave_sum64(qc);
        float den = 1.0f + dv + EPSF;
        float cu = bq + (dv * bq - aq) / den;
        float cw = -aq - (bq - dv * aq) / den;
        out_q[(size_t)row * DIM + lane] = qc + uvv * cu + V_VAL * cw;

        float diff = xv - qc;
        lsum += diff * diff;
        if (lane == 0) out_idx[row] = (float)idx;
    }
    lsum = wave_sum64(lsum);
    if (lane == 0) s_part[w] = lsum;
    __syncthreads();
    if (tid == 0) {
        float t = 0.f;
#pragma unroll
        for (int i = 0; i < 8; ++i) t += s_part[i];
        atomicAdd(out_loss, t * (1.0f + BETA) * (1.0f / (float)B_ROWS));
    }
}

extern "C" void kernel_launch(void* const* d_in, const int* in_sizes, int n_in,
                              void* d_out, int out_size, void* d_ws, size_t ws_size,
                              hipStream_t stream) {
    const float* x     = (const float*)d_in[0];
    const float* pq    = (const float*)d_in[1];
    const float* codes = (const float*)d_in[2];

    float* out      = (float*)d_out;
    float* out_q    = out;                         // B*D
    float* out_idx  = out + (size_t)B_ROWS * DIM;  // B
    float* out_loss = out_idx + B_ROWS;            // 1

    char* ws = (char*)d_ws;
    const size_t MB = 1024 * 1024;
    float* uo            = (float*)ws;                          // 2 MB
    float* duv           = (float*)(ws + 2 * MB);               // 32 KB
    float* cn            = (float*)(ws + 2 * MB + 64 * 1024);   // 8 KB
    unsigned short* xfrg = (unsigned short*)(ws + 3 * MB);      // 3 MB
    unsigned short* cfrg = (unsigned short*)(ws + 6 * MB);      // 768 KB
    float* pd            = (float*)(ws + 7 * MB);               // 512 KB
    int*   pi            = (int*)(ws + 7 * MB + 512 * 1024);    // 512 KB

    rq_prep<<<NCODES / 4 + B_ROWS / 4, 256, 0, stream>>>(
        x, pq, codes, cn, cfrg, xfrg, uo, duv, out_loss);
    rq_dist_mfma<<<(B_ROWS / 128) * NSPLIT, 256, 0, stream>>>(
        xfrg, cfrg, cn, pd, pi);
    rq_epilogue<<<B_ROWS / 64, 512, 0, stream>>>(
        x, codes, uo, duv, pd, pi, out_q, out_idx, out_loss);
}

// Round 6
// 96.711 us; speedup vs baseline: 2.3276x; 1.0034x over previous
//
#include <hip/hip_runtime.h>
#include <math.h>

#define B_ROWS 8192
#define DIM 64
#define NCODES 2048
#define NSPLIT 16                             // code-range splits (split-K)
#define CODES_PER_SPLIT (NCODES / NSPLIT)     // 128
#define TILES_PER_WAVE (CODES_PER_SPLIT / 16) // 8 tiles of 16 codes
#define EPSF 1e-6f
#define BETA 0.25f
#define V_VAL 0.125f                          // 1/sqrt(64)

typedef __attribute__((ext_vector_type(8))) short sh8;    // 8 bf16 = 4 VGPR
typedef __attribute__((ext_vector_type(4))) float f32x4;  // MFMA acc

__device__ __forceinline__ float wave_sum64(float v) {
#pragma unroll
    for (int m = 32; m >= 1; m >>= 1) v += __shfl_xor(v, m, 64);
    return v;
}

// RNE float -> bf16 bit trick (inputs finite)
__device__ __forceinline__ unsigned short f2bf(float f) {
    unsigned u = __float_as_uint(f);
    unsigned r = (u + 0x7fffu + ((u >> 16) & 1u)) >> 16;
    return (unsigned short)r;
}
__device__ __forceinline__ float bf2f(unsigned short h) {
    return __uint_as_float(((unsigned)h) << 16);
}

// Fragment layout (verified R3): frag #((tile16*3 + split)*2 + khalf) is
// 64 lanes x 16B; element (lane, j) = split_s(src[tile16*16 + (lane&15)]
// [khalf*32 + (lane>>4)*8 + j]).
__device__ __forceinline__ void write_frag3(unsigned short* frag, int rc,
                                            int dim, float val) {
    unsigned short s0 = f2bf(val);
    float r = val - bf2f(s0);
    unsigned short s1 = f2bf(r);
    r -= bf2f(s1);
    unsigned short s2 = f2bf(r);
    int t = rc >> 4, m = rc & 15;
    int h = dim >> 5, q = (dim >> 3) & 3, j = dim & 7;
    int lanep = q * 16 + m;
    size_t base = ((size_t)(t * 3) * 2 + h) * 512 + (size_t)lanep * 8 + j;
    frag[base] = s0;
    frag[base + 2 * 512] = s1;
    frag[base + 4 * 512] = s2;
}

// Kernel 1: fused prep. Blocks [0,512): code norms + bf16x3 code fragments
// (+ zero loss). Blocks [512,2560): row rotation factors + x_canonical
// fragments (rank-2 R^T x, R never materialized). Reductions use 4
// independent butterfly chains for ILP (shfl latency ~25 cyc hides 4-way).
__global__ __launch_bounds__(256) void rq_prep(
        const float* __restrict__ x,
        const float* __restrict__ pq,
        const float* __restrict__ codes,
        float* __restrict__ cn,
        unsigned short* __restrict__ cfrag,
        unsigned short* __restrict__ xfrag,
        float* __restrict__ uo,
        float* __restrict__ duv,
        float* __restrict__ out_loss) {
    int tid = threadIdx.x;
    int lane = tid & 63;
    int w = tid >> 6;

    if (blockIdx.x < NCODES / 4) {
        int c = blockIdx.x * 4 + w;
        float cv = codes[(size_t)c * DIM + lane];
        float s = wave_sum64(cv * cv);
        if (lane == 0) cn[c] = s;
        write_frag3(cfrag, c, lane, cv);
        if (blockIdx.x == 0 && tid == 0) *out_loss = 0.0f;
    } else {
        int r = (blockIdx.x - NCODES / 4) * 4 + w;
        float xv = x[(size_t)r * DIM + lane];
        float qv = pq[(size_t)r * DIM + lane];
        // 4 independent reductions: sum(q^2), sum(q), sum(q*x), sum(x)
        float sqq = qv * qv, sq = qv, sqx = qv * xv, sx = xv;
#pragma unroll
        for (int m = 32; m >= 1; m >>= 1) {
            sqq += __shfl_xor(sqq, m, 64);
            sq  += __shfl_xor(sq,  m, 64);
            sqx += __shfl_xor(sqx, m, 64);
            sx  += __shfl_xor(sx,  m, 64);
        }
        float inv = 1.0f / fmaxf(sqrtf(sqq), EPSF);
        float uv = qv * inv;
        float d = V_VAL * sq * inv;        // u.v
        float a = inv * sqx;               // u.x
        float b = V_VAL * sx;              // v.x
        float den = 1.0f + d + EPSF;
        float cu = -b + (d * b - a) / den;
        float cv = a - (b - d * a) / den;
        float xcv = xv + uv * cu + V_VAL * cv;
        uo[(size_t)r * DIM + lane] = uv;
        if (lane == 0) duv[r] = d;
        write_frag3(xfrag, r, lane, xcv);
    }
}

// Kernel 2: MFMA distance scan with LDS-staged B-fragments.
// Block = 128 rows x 128 codes (grid 64x16). B-frags (48 KB) staged in two
// 24 KB chunks: global->reg->ds_write_b128 once per block, inner loop reads
// ds_read_b128 (kills the 4x per-wave L2 refetch + in-loop load latency).
// Wave = 32 rows (2 A-tile sets resident, 48 VGPRs) x 16-code tiles;
// 6 split-products x 2 K-halves per tile -> exact-fp32-class dot.
__global__ __launch_bounds__(256) void rq_dist_mfma(
        const unsigned short* __restrict__ xfrag,
        const unsigned short* __restrict__ cfrag,
        const float* __restrict__ cn,
        float* __restrict__ pd,
        int* __restrict__ pi) {
    __shared__ sh8 sB[24 * 64];   // 4 tiles * 6 frags * 64 lanes * 16B = 24 KB

    int tid = threadIdx.x;
    int lane = tid & 63;
    int w = tid >> 6;
    int rb = blockIdx.x >> 4;     // 64 row-blocks of 128 rows
    int cs = blockIdx.x & (NSPLIT - 1);
    int r0 = rb * 128 + w * 32;
    int rt0 = r0 >> 4;
    int ct0 = cs * TILES_PER_WAVE;   // first 16-code tile of this split

    const sh8* xf = (const sh8*)xfrag;
    const sh8* cf = (const sh8*)cfrag;

    sh8 afr[2][3][2];
#pragma unroll
    for (int rs = 0; rs < 2; ++rs)
#pragma unroll
        for (int s = 0; s < 3; ++s)
#pragma unroll
            for (int h = 0; h < 2; ++h)
                afr[rs][s][h] = xf[(size_t)(((rt0 + rs) * 3 + s) * 2 + h) * 64 + lane];

    float bv0[4], bv1[4];
    int bi0[4], bi1[4];
#pragma unroll
    for (int i = 0; i < 4; ++i) {
        bv0[i] = INFINITY; bv1[i] = INFINITY;
        bi0[i] = 0x7fffffff; bi1[i] = 0x7fffffff;
    }

    int cbase = cs * CODES_PER_SPLIT;
#pragma unroll
    for (int ch = 0; ch < 2; ++ch) {
        // stage chunk ch: tiles [4ch, 4ch+4), 24 frags; wave w stages tile
        // tloc=w's 6 frags (slot = tloc*6 + s*2 + h matches reader index).
        {
            int tloc = w;
#pragma unroll
            for (int sh = 0; sh < 6; ++sh) {
                int fid = ((ct0 + ch * 4 + tloc) * 3 + (sh >> 1)) * 2 + (sh & 1);
                sB[(tloc * 6 + sh) * 64 + lane] = cf[(size_t)fid * 64 + lane];
            }
        }
        __syncthreads();

#pragma unroll
        for (int tloc = 0; tloc < 4; ++tloc) {
            int c0 = cbase + (ch * 4 + tloc) * 16;
            sh8 bfr[3][2];
#pragma unroll
            for (int s = 0; s < 3; ++s)
#pragma unroll
                for (int h = 0; h < 2; ++h)
                    bfr[s][h] = sB[(tloc * 6 + s * 2 + h) * 64 + lane];

            f32x4 acc0 = {0.f, 0.f, 0.f, 0.f};
            f32x4 acc1 = {0.f, 0.f, 0.f, 0.f};
#pragma unroll
            for (int h = 0; h < 2; ++h) {
                acc0 = __builtin_amdgcn_mfma_f32_16x16x32_bf16(afr[0][2][h], bfr[0][h], acc0, 0, 0, 0);
                acc0 = __builtin_amdgcn_mfma_f32_16x16x32_bf16(afr[0][1][h], bfr[1][h], acc0, 0, 0, 0);
                acc0 = __builtin_amdgcn_mfma_f32_16x16x32_bf16(afr[0][0][h], bfr[2][h], acc0, 0, 0, 0);
                acc0 = __builtin_amdgcn_mfma_f32_16x16x32_bf16(afr[0][1][h], bfr[0][h], acc0, 0, 0, 0);
                acc0 = __builtin_amdgcn_mfma_f32_16x16x32_bf16(afr[0][0][h], bfr[1][h], acc0, 0, 0, 0);
                acc0 = __builtin_amdgcn_mfma_f32_16x16x32_bf16(afr[0][0][h], bfr[0][h], acc0, 0, 0, 0);

                acc1 = __builtin_amdgcn_mfma_f32_16x16x32_bf16(afr[1][2][h], bfr[0][h], acc1, 0, 0, 0);
                acc1 = __builtin_amdgcn_mfma_f32_16x16x32_bf16(afr[1][1][h], bfr[1][h], acc1, 0, 0, 0);
                acc1 = __builtin_amdgcn_mfma_f32_16x16x32_bf16(afr[1][0][h], bfr[2][h], acc1, 0, 0, 0);
                acc1 = __builtin_amdgcn_mfma_f32_16x16x32_bf16(afr[1][1][h], bfr[0][h], acc1, 0, 0, 0);
                acc1 = __builtin_amdgcn_mfma_f32_16x16x32_bf16(afr[1][0][h], bfr[1][h], acc1, 0, 0, 0);
                acc1 = __builtin_amdgcn_mfma_f32_16x16x32_bf16(afr[1][0][h], bfr[0][h], acc1, 0, 0, 0);
            }

            float cnv = cn[c0 + (lane & 15)];
            int idxv = c0 + (lane & 15);
#pragma unroll
            for (int reg = 0; reg < 4; ++reg) {
                float s0 = fmaf(-2.0f, acc0[reg], cnv);
                if (s0 < bv0[reg]) { bv0[reg] = s0; bi0[reg] = idxv; }
                float s1 = fmaf(-2.0f, acc1[reg], cnv);
                if (s1 < bv1[reg]) { bv1[reg] = s1; bi1[reg] = idxv; }
            }
        }
        __syncthreads();   // before re-staging the shared buffer
    }

    // Per-row 16-col reduction (lexicographic -> first-occurrence).
#pragma unroll
    for (int rs = 0; rs < 2; ++rs) {
#pragma unroll
        for (int reg = 0; reg < 4; ++reg) {
            float v = rs ? bv1[reg] : bv0[reg];
            int ix = rs ? bi1[reg] : bi0[reg];
#pragma unroll
            for (int m = 1; m < 16; m <<= 1) {
                float ov = __shfl_xor(v, m, 64);
                int oi = __shfl_xor(ix, m, 64);
                if (ov < v || (ov == v && oi < ix)) { v = ov; ix = oi; }
            }
            int row = r0 + rs * 16 + (lane >> 4) * 4 + reg;
            if ((lane & 15) == reg) {
                pd[(size_t)row * NSPLIT + cs] = v;
                pi[(size_t)row * NSPLIT + cs] = ix;
            }
        }
    }
}

// Kernel 3: fused epilogue + loss. 128 blocks x 512 threads (8 waves).
// Wave handles 8 rows: combine 16 partials/row (one cache line), gather
// code, rotate back (rank-2 R q), write quantized + index, accumulate
// loss; block-reduce -> ONE atomicAdd per block (128 total).
__global__ __launch_bounds__(512) void rq_epilogue(
        const float* __restrict__ x,
        const float* __restrict__ codes,
        const float* __restrict__ uo,
        const float* __restrict__ duv,
        const float* __restrict__ pd,
        const int* __restrict__ pi,
        float* __restrict__ out_q,
        float* __restrict__ out_idx,
        float* __restrict__ out_loss) {
    __shared__ float s_part[8];
    int tid = threadIdx.x;
    int lane = tid & 63;
    int w = tid >> 6;
    int row0 = blockIdx.x * 64 + w * 8;

    float lsum = 0.f;
#pragma unroll
    for (int i = 0; i < 8; ++i) {
        int row = row0 + i;
        float pv = INFINITY;
        int iv = 0x7fffffff;
        if (lane < NSPLIT) {
            pv = pd[(size_t)row * NSPLIT + lane];
            iv = pi[(size_t)row * NSPLIT + lane];
        }
#pragma unroll
        for (int m = 1; m < NSPLIT; m <<= 1) {
            float ov = __shfl_xor(pv, m, 64);
            int oi = __shfl_xor(iv, m, 64);
            if (ov < pv || (ov == pv && oi < iv)) { pv = ov; iv = oi; }
        }
        int idx = __shfl(iv, 0, 64);

        float qc = codes[(size_t)idx * DIM + lane];
        float uvv = uo[(size_t)row * DIM + lane];
        float xv = x[(size_t)row * DIM + lane];
        float dv = duv[row];

        float aq = wave_sum64(uvv * qc);
        float bq = V_VAL * wave_sum64(qc);
        float den = 1.0f + dv + EPSF;
        float cu = bq + (dv * bq - aq) / den;
        float cw = -aq - (bq - dv * aq) / den;
        out_q[(size_t)row * DIM + lane] = qc + uvv * cu + V_VAL * cw;

        float diff = xv - qc;
        lsum += diff * diff;
        if (lane == 0) out_idx[row] = (float)idx;
    }
    lsum = wave_sum64(lsum);
    if (lane == 0) s_part[w] = lsum;
    __syncthreads();
    if (tid == 0) {
        float t = 0.f;
#pragma unroll
        for (int i = 0; i < 8; ++i) t += s_part[i];
        atomicAdd(out_loss, t * (1.0f + BETA) * (1.0f / (float)B_ROWS));
    }
}

extern "C" void kernel_launch(void* const* d_in, const int* in_sizes, int n_in,
                              void* d_out, int out_size, void* d_ws, size_t ws_size,
                              hipStream_t stream) {
    const float* x     = (const float*)d_in[0];
    const float* pq    = (const float*)d_in[1];
    const float* codes = (const float*)d_in[2];

    float* out      = (float*)d_out;
    float* out_q    = out;                         // B*D
    float* out_idx  = out + (size_t)B_ROWS * DIM;  // B
    float* out_loss = out_idx + B_ROWS;            // 1

    char* ws = (char*)d_ws;
    const size_t MB = 1024 * 1024;
    float* uo            = (float*)ws;                          // 2 MB
    float* duv           = (float*)(ws + 2 * MB);               // 32 KB
    float* cn            = (float*)(ws + 2 * MB + 64 * 1024);   // 8 KB
    unsigned short* xfrg = (unsigned short*)(ws + 3 * MB);      // 3 MB
    unsigned short* cfrg = (unsigned short*)(ws + 6 * MB);      // 768 KB
    float* pd            = (float*)(ws + 7 * MB);               // 512 KB
    int*   pi            = (int*)(ws + 7 * MB + 512 * 1024);    // 512 KB

    rq_prep<<<NCODES / 4 + B_ROWS / 4, 256, 0, stream>>>(
        x, pq, codes, cn, cfrg, xfrg, uo, duv, out_loss);
    rq_dist_mfma<<<(B_ROWS / 128) * NSPLIT, 256, 0, stream>>>(
        xfrg, cfrg, cn, pd, pi);
    rq_epilogue<<<B_ROWS / 64, 512, 0, stream>>>(
        x, codes, uo, duv, pd, pi, out_q, out_idx, out_loss);
}

// Round 8
// 93.165 us; speedup vs baseline: 2.4162x; 1.0381x over previous
//
#include <hip/hip_runtime.h>
#include <math.h>

#define B_ROWS 8192
#define DIM 64
#define NCODES 2048
#define NSPLIT 16                             // code-range splits (split-K)
#define CODES_PER_SPLIT (NCODES / NSPLIT)     // 128
#define TILES_PER_WAVE (CODES_PER_SPLIT / 16) // 8 tiles of 16 codes
#define EPSF 1e-6f
#define BETA 0.25f
#define V_VAL 0.125f                          // 1/sqrt(64)

typedef __attribute__((ext_vector_type(8))) short sh8;    // 8 bf16 = 4 VGPR
typedef __attribute__((ext_vector_type(4))) float f32x4;  // MFMA acc

__device__ __forceinline__ float wave_sum64(float v) {
#pragma unroll
    for (int m = 32; m >= 1; m >>= 1) v += __shfl_xor(v, m, 64);
    return v;
}

// RNE float -> bf16 bit trick (inputs finite)
__device__ __forceinline__ unsigned short f2bf(float f) {
    unsigned u = __float_as_uint(f);
    unsigned r = (u + 0x7fffu + ((u >> 16) & 1u)) >> 16;
    return (unsigned short)r;
}
__device__ __forceinline__ float bf2f(unsigned short h) {
    return __uint_as_float(((unsigned)h) << 16);
}

// Fragment layout (verified R3): frag #((tile16*3 + split)*2 + khalf) is
// 64 lanes x 16B; element (lane, j) = split_s(src[tile16*16 + (lane&15)]
// [khalf*32 + (lane>>4)*8 + j]).
__device__ __forceinline__ void write_frag3(unsigned short* frag, int rc,
                                            int dim, float val) {
    unsigned short s0 = f2bf(val);
    float r = val - bf2f(s0);
    unsigned short s1 = f2bf(r);
    r -= bf2f(s1);
    unsigned short s2 = f2bf(r);
    int t = rc >> 4, m = rc & 15;
    int h = dim >> 5, q = (dim >> 3) & 3, j = dim & 7;
    int lanep = q * 16 + m;
    size_t base = ((size_t)(t * 3) * 2 + h) * 512 + (size_t)lanep * 8 + j;
    frag[base] = s0;
    frag[base + 2 * 512] = s1;
    frag[base + 4 * 512] = s2;
}

// Kernel 1: fused prep. Blocks [0,512): code norms + bf16x3 code fragments
// (+ zero loss). Blocks [512,2560): row rotation factors + x_canonical
// fragments (rank-2 R^T x, R never materialized). 4 independent butterfly
// chains for reduction ILP.
__global__ __launch_bounds__(256) void rq_prep(
        const float* __restrict__ x,
        const float* __restrict__ pq,
        const float* __restrict__ codes,
        float* __restrict__ cn,
        unsigned short* __restrict__ cfrag,
        unsigned short* __restrict__ xfrag,
        float* __restrict__ uo,
        float* __restrict__ duv,
        float* __restrict__ out_loss) {
    int tid = threadIdx.x;
    int lane = tid & 63;
    int w = tid >> 6;

    if (blockIdx.x < NCODES / 4) {
        int c = blockIdx.x * 4 + w;
        float cv = codes[(size_t)c * DIM + lane];
        float s = wave_sum64(cv * cv);
        if (lane == 0) cn[c] = s;
        write_frag3(cfrag, c, lane, cv);
        if (blockIdx.x == 0 && tid == 0) *out_loss = 0.0f;
    } else {
        int r = (blockIdx.x - NCODES / 4) * 4 + w;
        float xv = x[(size_t)r * DIM + lane];
        float qv = pq[(size_t)r * DIM + lane];
        float sqq = qv * qv, sq = qv, sqx = qv * xv, sx = xv;
#pragma unroll
        for (int m = 32; m >= 1; m >>= 1) {
            sqq += __shfl_xor(sqq, m, 64);
            sq  += __shfl_xor(sq,  m, 64);
            sqx += __shfl_xor(sqx, m, 64);
            sx  += __shfl_xor(sx,  m, 64);
        }
        float inv = 1.0f / fmaxf(sqrtf(sqq), EPSF);
        float uv = qv * inv;
        float d = V_VAL * sq * inv;        // u.v
        float a = inv * sqx;               // u.x
        float b = V_VAL * sx;              // v.x
        float den = 1.0f + d + EPSF;
        float cu = -b + (d * b - a) / den;
        float cv = a - (b - d * a) / den;
        float xcv = xv + uv * cu + V_VAL * cv;
        uo[(size_t)r * DIM + lane] = uv;
        if (lane == 0) duv[r] = d;
        write_frag3(xfrag, r, lane, xcv);
    }
}

// Kernel 2: MFMA distance scan (R3's proven structure, global B loads).
// Wave = 32 rows (2 A-tile sets, bf16x3 resident in 48 VGPRs) x 128 codes
// (8 tiles of 16). 6 split-products x 2 K-halves chained into fp32 acc ->
// exact-fp32-class dot. Partials at pd[row*16+cs].
__global__ __launch_bounds__(256) void rq_dist_mfma(
        const unsigned short* __restrict__ xfrag,
        const unsigned short* __restrict__ cfrag,
        const float* __restrict__ cn,
        float* __restrict__ pd,
        int* __restrict__ pi) {
    int tid = threadIdx.x;
    int lane = tid & 63;
    int w = tid >> 6;
    int rb = blockIdx.x >> 4;     // 64 row-blocks of 128 rows
    int cs = blockIdx.x & (NSPLIT - 1);
    int r0 = rb * 128 + w * 32;
    int rt0 = r0 >> 4;

    const sh8* xf = (const sh8*)xfrag;
    const sh8* cf = (const sh8*)cfrag;

    sh8 afr[2][3][2];
#pragma unroll
    for (int rs = 0; rs < 2; ++rs)
#pragma unroll
        for (int s = 0; s < 3; ++s)
#pragma unroll
            for (int h = 0; h < 2; ++h)
                afr[rs][s][h] = xf[(size_t)(((rt0 + rs) * 3 + s) * 2 + h) * 64 + lane];

    float bv0[4], bv1[4];
    int bi0[4], bi1[4];
#pragma unroll
    for (int i = 0; i < 4; ++i) {
        bv0[i] = INFINITY; bv1[i] = INFINITY;
        bi0[i] = 0x7fffffff; bi1[i] = 0x7fffffff;
    }

    int cbase = cs * CODES_PER_SPLIT;
    for (int t = 0; t < TILES_PER_WAVE; ++t) {
        int c0 = cbase + t * 16;
        int ct = c0 >> 4;
        sh8 bfr[3][2];
#pragma unroll
        for (int s = 0; s < 3; ++s)
#pragma unroll
            for (int h = 0; h < 2; ++h)
                bfr[s][h] = cf[(size_t)((ct * 3 + s) * 2 + h) * 64 + lane];

        f32x4 acc0 = {0.f, 0.f, 0.f, 0.f};
        f32x4 acc1 = {0.f, 0.f, 0.f, 0.f};
#pragma unroll
        for (int h = 0; h < 2; ++h) {
            acc0 = __builtin_amdgcn_mfma_f32_16x16x32_bf16(afr[0][2][h], bfr[0][h], acc0, 0, 0, 0);
            acc0 = __builtin_amdgcn_mfma_f32_16x16x32_bf16(afr[0][1][h], bfr[1][h], acc0, 0, 0, 0);
            acc0 = __builtin_amdgcn_mfma_f32_16x16x32_bf16(afr[0][0][h], bfr[2][h], acc0, 0, 0, 0);
            acc0 = __builtin_amdgcn_mfma_f32_16x16x32_bf16(afr[0][1][h], bfr[0][h], acc0, 0, 0, 0);
            acc0 = __builtin_amdgcn_mfma_f32_16x16x32_bf16(afr[0][0][h], bfr[1][h], acc0, 0, 0, 0);
            acc0 = __builtin_amdgcn_mfma_f32_16x16x32_bf16(afr[0][0][h], bfr[0][h], acc0, 0, 0, 0);

            acc1 = __builtin_amdgcn_mfma_f32_16x16x32_bf16(afr[1][2][h], bfr[0][h], acc1, 0, 0, 0);
            acc1 = __builtin_amdgcn_mfma_f32_16x16x32_bf16(afr[1][1][h], bfr[1][h], acc1, 0, 0, 0);
            acc1 = __builtin_amdgcn_mfma_f32_16x16x32_bf16(afr[1][0][h], bfr[2][h], acc1, 0, 0, 0);
            acc1 = __builtin_amdgcn_mfma_f32_16x16x32_bf16(afr[1][1][h], bfr[0][h], acc1, 0, 0, 0);
            acc1 = __builtin_amdgcn_mfma_f32_16x16x32_bf16(afr[1][0][h], bfr[1][h], acc1, 0, 0, 0);
            acc1 = __builtin_amdgcn_mfma_f32_16x16x32_bf16(afr[1][0][h], bfr[0][h], acc1, 0, 0, 0);
        }

        float cnv = cn[c0 + (lane & 15)];
        int idxv = c0 + (lane & 15);
#pragma unroll
        for (int reg = 0; reg < 4; ++reg) {
            float s0 = fmaf(-2.0f, acc0[reg], cnv);
            if (s0 < bv0[reg]) { bv0[reg] = s0; bi0[reg] = idxv; }
            float s1 = fmaf(-2.0f, acc1[reg], cnv);
            if (s1 < bv1[reg]) { bv1[reg] = s1; bi1[reg] = idxv; }
        }
    }

    // Per-row 16-col reduction (lexicographic -> first-occurrence).
#pragma unroll
    for (int rs = 0; rs < 2; ++rs) {
#pragma unroll
        for (int reg = 0; reg < 4; ++reg) {
            float v = rs ? bv1[reg] : bv0[reg];
            int ix = rs ? bi1[reg] : bi0[reg];
#pragma unroll
            for (int m = 1; m < 16; m <<= 1) {
                float ov = __shfl_xor(v, m, 64);
                int oi = __shfl_xor(ix, m, 64);
                if (ov < v || (ov == v && oi < ix)) { v = ov; ix = oi; }
            }
            int row = r0 + rs * 16 + (lane >> 4) * 4 + reg;
            if ((lane & 15) == reg) {
                pd[(size_t)row * NSPLIT + cs] = v;
                pi[(size_t)row * NSPLIT + cs] = ix;
            }
        }
    }
}

// Kernel 3: epilogue, widened: 1024 blocks x 256 threads, 2 rows per wave
// (4096 waves = 16/CU -> the serial cross-XCD-load + gather + wave_sum
// chain per row is latency-hidden by TLP). Per-wave loss partial to lossp
// (no atomics).
__global__ __launch_bounds__(256) void rq_epilogue(
        const float* __restrict__ x,
        const float* __restrict__ codes,
        const float* __restrict__ uo,
        const float* __restrict__ duv,
        const float* __restrict__ pd,
        const int* __restrict__ pi,
        float* __restrict__ out_q,
        float* __restrict__ out_idx,
        float* __restrict__ lossp) {
    int tid = threadIdx.x;
    int lane = tid & 63;
    int w = tid >> 6;
    int gw = blockIdx.x * 4 + w;    // 0..4095

    float lsum = 0.f;
#pragma unroll
    for (int i = 0; i < 2; ++i) {
        int row = gw * 2 + i;
        float pv = INFINITY;
        int iv = 0x7fffffff;
        if (lane < NSPLIT) {
            pv = pd[(size_t)row * NSPLIT + lane];
            iv = pi[(size_t)row * NSPLIT + lane];
        }
#pragma unroll
        for (int m = 1; m < NSPLIT; m <<= 1) {
            float ov = __shfl_xor(pv, m, 64);
            int oi = __shfl_xor(iv, m, 64);
            if (ov < pv || (ov == pv && oi < iv)) { pv = ov; iv = oi; }
        }
        int idx = __shfl(iv, 0, 64);

        float qc = codes[(size_t)idx * DIM + lane];
        float uvv = uo[(size_t)row * DIM + lane];
        float xv = x[(size_t)row * DIM + lane];
        float dv = duv[row];

        float aq = wave_sum64(uvv * qc);
        float bq = V_VAL * wave_sum64(qc);
        float den = 1.0f + dv + EPSF;
        float cu = bq + (dv * bq - aq) / den;
        float cw = -aq - (bq - dv * aq) / den;
        out_q[(size_t)row * DIM + lane] = qc + uvv * cu + V_VAL * cw;

        float diff = xv - qc;
        lsum += diff * diff;
        if (lane == 0) out_idx[row] = (float)idx;
    }
    lsum = wave_sum64(lsum);
    if (lane == 0) lossp[gw] = lsum;
}

// Kernel 4: single-block sum of 4096 per-wave loss partials.
__global__ void rq_loss_reduce(const float* __restrict__ lossp,
                               float* __restrict__ out_loss) {
    __shared__ float part[16];
    int tid = threadIdx.x;  // 1024 threads
    float s = 0.f;
#pragma unroll
    for (int i = 0; i < 4096 / 1024; ++i) s += lossp[tid + i * 1024];
    s = wave_sum64(s);
    if ((tid & 63) == 0) part[tid >> 6] = s;
    __syncthreads();
    if (tid < 64) {
        float v = (tid < 16) ? part[tid] : 0.f;
        v = wave_sum64(v);
        if (tid == 0) *out_loss = v * (1.0f + BETA) * (1.0f / (float)B_ROWS);
    }
}

extern "C" void kernel_launch(void* const* d_in, const int* in_sizes, int n_in,
                              void* d_out, int out_size, void* d_ws, size_t ws_size,
                              hipStream_t stream) {
    const float* x     = (const float*)d_in[0];
    const float* pq    = (const float*)d_in[1];
    const float* codes = (const float*)d_in[2];

    float* out      = (float*)d_out;
    float* out_q    = out;                         // B*D
    float* out_idx  = out + (size_t)B_ROWS * DIM;  // B
    float* out_loss = out_idx + B_ROWS;            // 1

    char* ws = (char*)d_ws;
    const size_t MB = 1024 * 1024;
    float* uo            = (float*)ws;                          // 2 MB
    float* duv           = (float*)(ws + 2 * MB);               // 32 KB
    float* cn            = (float*)(ws + 2 * MB + 64 * 1024);   // 8 KB
    float* lossp         = (float*)(ws + 2 * MB + 128 * 1024);  // 16 KB
    unsigned short* xfrg = (unsigned short*)(ws + 3 * MB);      // 3 MB
    unsigned short* cfrg = (unsigned short*)(ws + 6 * MB);      // 768 KB
    float* pd            = (float*)(ws + 7 * MB);               // 512 KB
    int*   pi            = (int*)(ws + 7 * MB + 512 * 1024);    // 512 KB

    rq_prep<<<NCODES / 4 + B_ROWS / 4, 256, 0, stream>>>(
        x, pq, codes, cn, cfrg, xfrg, uo, duv, out_loss);
    rq_dist_mfma<<<(B_ROWS / 128) * NSPLIT, 256, 0, stream>>>(
        xfrg, cfrg, cn, pd, pi);
    rq_epilogue<<<B_ROWS / 8, 256, 0, stream>>>(
        x, codes, uo, duv, pd, pi, out_q, out_idx, lossp);
    rq_loss_reduce<<<1, 1024, 0, stream>>>(lossp, out_loss);
}